// Round 4
// 2275.782 us; speedup vs baseline: 1.0328x; 1.0328x over previous
//
#include <hip/hip_runtime.h>
#include <cstdint>
#include <cstddef>

// ---------------------------------------------------------------------------
// R_GAMLP_RLU: H=10 hops, N=100000 nodes, F=256, HID=512, C=47.
//   attn_kernel : wave-per-node; xl/xr dots + softmax recursion in fp32,
//                 right = sum att_h * f_h  -> bf16 (N x 256)
//   uber_pack   : ALL weight packs + label_emb pack in ONE launch
//                 (w_last & wl3 packed into one [64][1024] B^T for fused final)
//   gemm_dual   : m97-style 128x128 bf16 MFMA GEMM; template EA/EB epilogues;
//                 grid y=8: y<4 -> problem A, y>=4 -> problem B (dual launch)
//                 grid y=4: problem A only (sequential fallback)
//   gemm_final  : concat-K (1024) GEMM  out = [p2|y2] @ [w_last;wl3] + biases
// Host branches on ws_size:
//   >= 681 MB : 6-launch dual schedule   (primary experiment)
//   >= 477 MB : 9-launch sequential, 4 live N*512 buffers (proven-size hedge)
// ---------------------------------------------------------------------------

#define DEVI __device__ __forceinline__

typedef __attribute__((ext_vector_type(4))) float fx4;
typedef __attribute__((ext_vector_type(8))) short sx8;

constexpr int NN = 100000;   // nodes (M dimension of all GEMMs)

DEVI unsigned short f2b(float f) {   // fp32 -> bf16 RNE (no NaNs in this net)
  unsigned u = __float_as_uint(f);
  u = (u + 0x7fffu + ((u >> 16) & 1u)) >> 16;
  return (unsigned short)u;
}
DEVI float b2f(short v) {
  return __uint_as_float(((unsigned)(unsigned short)v) << 16);
}

// async global->LDS, 16B per lane (dest must be base + lane*16, no padding)
#define GLDS16(gp, lp) __builtin_amdgcn_global_load_lds( \
    (__attribute__((address_space(1))) void*)(void*)(gp), \
    (__attribute__((address_space(3))) void*)(lp), 16, 0, 0)

// ---------------------------------------------------------------------------
// Attention stage (unchanged — verified). One wave per node.
// ---------------------------------------------------------------------------
__global__ __launch_bounds__(256)
void attn_kernel(const float* __restrict__ feat, const float* __restrict__ wa,
                 const float* __restrict__ baP, short* __restrict__ right) {
  const int lane = threadIdx.x & 63;
  const int n = blockIdx.x * 4 + (threadIdx.x >> 6);   // 25000*4 == 100000 exactly
  const float ba = *baP;
  const fx4 wl4 = *(const fx4*)(wa + lane * 4);
  const fx4 wr4 = *(const fx4*)(wa + 256 + lane * 4);
  fx4 f[10];
  float xl[10], xr[10];
#pragma unroll
  for (int h = 0; h < 10; h++) {
    f[h] = *(const fx4*)(feat + ((long)h * NN + n) * 256 + lane * 4);
    float pl = f[h][0] * wl4[0] + f[h][1] * wl4[1] + f[h][2] * wl4[2] + f[h][3] * wl4[3];
    float pr = f[h][0] * wr4[0] + f[h][1] * wr4[1] + f[h][2] * wr4[2] + f[h][3] * wr4[3];
#pragma unroll
    for (int off = 32; off > 0; off >>= 1) {
      pl += __shfl_xor(pl, off);
      pr += __shfl_xor(pr, off);
    }
    xl[h] = pl; xr[h] = pr;
  }
  float e[10];
  float s = xl[0] + xr[0] + ba;
  s = s >= 0.f ? s : 0.2f * s;
  e[0] = __expf(s);
  float P = e[0] * xl[0], S = e[0];
#pragma unroll
  for (int i = 1; i < 10; i++) {
    float t = P / S + xr[i] + ba;
    t = t >= 0.f ? t : 0.2f * t;
    e[i] = __expf(t);
    P += e[i] * xl[i];
    S += e[i];
  }
  const float inv = 1.f / S;
  fx4 r = {0.f, 0.f, 0.f, 0.f};
#pragma unroll
  for (int h = 0; h < 10; h++) {
    const float w = e[h] * inv;
    r[0] += w * f[h][0]; r[1] += w * f[h][1];
    r[2] += w * f[h][2]; r[3] += w * f[h][3];
  }
  ushort4 o;
  o.x = f2b(r[0]); o.y = f2b(r[1]); o.z = f2b(r[2]); o.w = f2b(r[3]);
  *(ushort4*)(right + (long)n * 256 + lane * 4) = o;
}

// ---------------------------------------------------------------------------
// WP layout (shorts). All B^T matrices: dst[n][k] = src[k][n], zero-padded.
// ---------------------------------------------------------------------------
constexpr int W_W0  = 0;         // [512][256]
constexpr int W_WG1 = 131072;    // [512][512]
constexpr int W_WG2 = 393216;    // [512][512]
constexpr int W_WL0 = 655360;    // [512][64]  (K 47->64 zero-pad)
constexpr int W_WL1 = 688128;    // [512][512]
constexpr int W_WL2 = 950272;    // [512][512]
constexpr int W_FIN = 1212416;   // [64][1024]: cols 0..511 = w_last^T, 512..1023 = wl3^T
constexpr int W_END = 1277952;   // end of weight region (shorts)

// One kernel packs every weight matrix + label_emb. Region table compile-time.
__global__ __launch_bounds__(256)
void uber_pack(const float* __restrict__ w0,     const float* __restrict__ wg1,
               const float* __restrict__ wg2,    const float* __restrict__ wl0,
               const float* __restrict__ wl1,    const float* __restrict__ wl2,
               const float* __restrict__ w_last, const float* __restrict__ wl3,
               const float* __restrict__ lemb,
               short* __restrict__ WP, short* __restrict__ lab) {
  const long idx = (long)blockIdx.x * 256 + threadIdx.x;
  constexpr long LAB_END = (long)W_END + (long)NN * 64;
  if (idx >= LAB_END) return;
  if (idx < W_WG1) {                      // w0: [256][512] -> [512][256]
    int l = (int)idx, n = l >> 8, k = l & 255;
    WP[idx] = (short)f2b(w0[(long)k * 512 + n]);
  } else if (idx < W_WG2) {               // wg1: [512][512]
    int l = (int)(idx - W_WG1), n = l >> 9, k = l & 511;
    WP[idx] = (short)f2b(wg1[(long)k * 512 + n]);
  } else if (idx < W_WL0) {               // wg2
    int l = (int)(idx - W_WG2), n = l >> 9, k = l & 511;
    WP[idx] = (short)f2b(wg2[(long)k * 512 + n]);
  } else if (idx < W_WL1) {               // wl0: [47][512] -> [512][64], k pad
    int l = (int)(idx - W_WL0), n = l >> 6, k = l & 63;
    WP[idx] = (short)f2b(k < 47 ? wl0[(long)k * 512 + n] : 0.f);
  } else if (idx < W_WL2) {               // wl1
    int l = (int)(idx - W_WL1), n = l >> 9, k = l & 511;
    WP[idx] = (short)f2b(wl1[(long)k * 512 + n]);
  } else if (idx < W_FIN) {               // wl2
    int l = (int)(idx - W_WL2), n = l >> 9, k = l & 511;
    WP[idx] = (short)f2b(wl2[(long)k * 512 + n]);
  } else if (idx < W_FIN + 32768) {       // w_last: [512][47] -> FIN[n][k], n pad
    int l = (int)(idx - W_FIN), n = l >> 9, k = l & 511;
    WP[W_FIN + (long)n * 1024 + k] = (short)f2b(n < 47 ? w_last[(long)k * 47 + n] : 0.f);
  } else if (idx < W_END) {               // wl3: [512][47] -> FIN[n][512+k]
    int l = (int)(idx - (W_FIN + 32768)), n = l >> 9, k = l & 511;
    WP[W_FIN + (long)n * 1024 + 512 + k] = (short)f2b(n < 47 ? wl3[(long)k * 47 + n] : 0.f);
  } else {                                // label_emb: [N][47] -> lab [N][64]
    long l = idx - W_END;
    int n = (int)(l >> 6), k = (int)(l & 63);
    lab[l] = (short)f2b(k < 47 ? lemb[(long)n * 47 + k] : 0.f);
  }
}

// ---------------------------------------------------------------------------
// GEMM (m97 inner structure). Epilogues:
//  0: x0 = c + bias       -> out0=x0, out1=0.5*prelu(x0)+0.5*x0
//  1: x1 = c + prelu(x0)  -> out0=x1, out1=0.5*prelu(x1)+0.5*x0   (epiIn=x0)
//  2: x2 = c + prelu(x1)  -> out0=prelu(x2)                        (epiIn=x1)
//  4: out0 = prelu(c + bias)
// ---------------------------------------------------------------------------
struct GArgs {
  const short* A; const short* BT; int K;
  const float* bias; const short* epiIn;
  short* out0; short* out1; const float* alphaP;
};

template<int EPI>
DEVI void epilogue(const GArgs& g, const fx4 (&acc)[4][4],
                   int m0, int n0, int wm, int wn, int lane) {
  const float alpha = (g.alphaP != nullptr) ? *g.alphaP : 0.f;
#pragma unroll
  for (int i = 0; i < 4; i++) {
#pragma unroll
    for (int j = 0; j < 4; j++) {
#pragma unroll
      for (int r = 0; r < 4; r++) {
        const int m = m0 + wm * 64 + i * 16 + ((lane >> 4) << 2) + r;
        const int n = n0 + wn * 64 + j * 16 + (lane & 15);
        if (m >= NN) continue;
        float v = acc[i][j][r];
        const long o = (long)m * 512 + n;
        if constexpr (EPI == 0) {
          v += g.bias[n];
          g.out0[o] = (short)f2b(v);
          const float p = v >= 0.f ? v : alpha * v;
          g.out1[o] = (short)f2b(0.5f * p + 0.5f * v);
        } else if constexpr (EPI == 1) {
          const float x0v = b2f(g.epiIn[o]);
          const float xi = x0v >= 0.f ? x0v : alpha * x0v;
          const float x1 = v + xi;
          g.out0[o] = (short)f2b(x1);
          const float p1 = x1 >= 0.f ? x1 : alpha * x1;
          g.out1[o] = (short)f2b(0.5f * p1 + 0.5f * x0v);
        } else if constexpr (EPI == 2) {
          const float x1v = b2f(g.epiIn[o]);
          const float xi = x1v >= 0.f ? x1v : alpha * x1v;
          const float x2 = v + xi;
          g.out0[o] = (short)f2b(x2 >= 0.f ? x2 : alpha * x2);
        } else {  // EPI == 4
          const float y = v + g.bias[n];
          g.out0[o] = (short)f2b(y >= 0.f ? y : alpha * y);
        }
      }
    }
  }
}

template<int EA, int EB>
__global__ __launch_bounds__(256)
void gemm_dual(GArgs ga, GArgs gb) {
  constexpr int BM = 128, BN = 128, BK = 32;
  __shared__ short As[BM * BK];
  __shared__ short Bs[BN * BK];
  const bool second = (blockIdx.y >= 4);
  const short* __restrict__ A  = second ? gb.A  : ga.A;
  const short* __restrict__ BT = second ? gb.BT : ga.BT;
  const int K = second ? gb.K : ga.K;
  const int tid = threadIdx.x;
  const int wave = tid >> 6, lane = tid & 63;
  const int wm = wave >> 1, wn = wave & 1;
  const int m0 = blockIdx.x * BM;
  const int n0 = (blockIdx.y & 3) * BN;
  fx4 acc[4][4] = {};

  const int kIters = K / BK;
  for (int kk = 0; kk < kIters; kk++) {
    const int k0 = kk * BK;
#pragma unroll
    for (int c = 0; c < 2; c++) {                       // A tile: 2 x 16B/lane
      const int idx = c * 256 + tid;
      long row = m0 + (idx >> 2);
      if (row > NN - 1) row = NN - 1;                   // clamp M tail
      GLDS16(A + row * (long)K + k0 + ((idx & 3) << 3), As + idx * 8);
    }
#pragma unroll
    for (int c = 0; c < 2; c++) {                       // B tile
      const int idx = c * 256 + tid;
      GLDS16(BT + (long)(n0 + (idx >> 2)) * K + k0 + ((idx & 3) << 3), Bs + idx * 8);
    }
    __syncthreads();                                    // drains vmcnt before barrier
    sx8 af[4], bf[4];
#pragma unroll
    for (int i = 0; i < 4; i++)
      af[i] = *(const sx8*)(As + (wm * 64 + i * 16 + (lane & 15)) * BK + ((lane >> 4) << 3));
#pragma unroll
    for (int j = 0; j < 4; j++)
      bf[j] = *(const sx8*)(Bs + (wn * 64 + j * 16 + (lane & 15)) * BK + ((lane >> 4) << 3));
#pragma unroll
    for (int i = 0; i < 4; i++)
#pragma unroll
      for (int j = 0; j < 4; j++)
        acc[i][j] = __builtin_amdgcn_mfma_f32_16x16x32_bf16(af[i], bf[j], acc[i][j], 0, 0, 0);
    __syncthreads();
  }

  if (!second) epilogue<EA>(ga, acc, m0, n0, wm, wn, lane);
  else         epilogue<EB>(gb, acc, m0, n0, wm, wn, lane);
}

// ---------------------------------------------------------------------------
// Fused final: out[m][n<47] = p2[m,:]@w_last + y2[m,:]@wl3 + b_last + bl3.
// Concat-K=1024 (A-pointer switch at k=512), B^T = WP[W_FIN] ([64][1024]).
// ---------------------------------------------------------------------------
__global__ __launch_bounds__(256)
void gemm_final(const short* __restrict__ Ap, const short* __restrict__ Ay,
                const short* __restrict__ BT, const float* __restrict__ b1,
                const float* __restrict__ b2, float* __restrict__ outp) {
  constexpr int BM = 128, BN = 64, BK = 32, WN = 32;
  __shared__ short As[BM * BK];
  __shared__ short Bs[BN * BK];
  const int tid = threadIdx.x;
  const int wave = tid >> 6, lane = tid & 63;
  const int wm = wave >> 1, wn = wave & 1;
  const int m0 = blockIdx.x * BM;
  fx4 acc[4][2] = {};

  for (int kk = 0; kk < 32; kk++) {                     // K = 1024
    const int k0 = kk * BK;
    const short* __restrict__ Asel = (kk < 16) ? Ap : Ay;
    const int kl = k0 & 511;
#pragma unroll
    for (int c = 0; c < 2; c++) {
      const int idx = c * 256 + tid;
      long row = m0 + (idx >> 2);
      if (row > NN - 1) row = NN - 1;
      GLDS16(Asel + row * 512L + kl + ((idx & 3) << 3), As + idx * 8);
    }
    {                                                   // B: 64x32 = 1 chunk
      const int idx = tid;
      GLDS16(BT + (long)(idx >> 2) * 1024 + k0 + ((idx & 3) << 3), Bs + idx * 8);
    }
    __syncthreads();
    sx8 af[4], bf[2];
#pragma unroll
    for (int i = 0; i < 4; i++)
      af[i] = *(const sx8*)(As + (wm * 64 + i * 16 + (lane & 15)) * BK + ((lane >> 4) << 3));
#pragma unroll
    for (int j = 0; j < 2; j++)
      bf[j] = *(const sx8*)(Bs + (wn * WN + j * 16 + (lane & 15)) * BK + ((lane >> 4) << 3));
#pragma unroll
    for (int i = 0; i < 4; i++)
#pragma unroll
      for (int j = 0; j < 2; j++)
        acc[i][j] = __builtin_amdgcn_mfma_f32_16x16x32_bf16(af[i], bf[j], acc[i][j], 0, 0, 0);
    __syncthreads();
  }

#pragma unroll
  for (int i = 0; i < 4; i++)
#pragma unroll
    for (int j = 0; j < 2; j++)
#pragma unroll
      for (int r = 0; r < 4; r++) {
        const int m = m0 + wm * 64 + i * 16 + ((lane >> 4) << 2) + r;
        const int n = wn * WN + j * 16 + (lane & 15);
        if (m < NN && n < 47)
          outp[(long)m * 47 + n] = acc[i][j][r] + b1[n] + b2[n];
      }
}

// ---------------------------------------------------------------------------
// Workspace layout (bytes).
//   common: WP (2.56 MB) | right 51.2 MB | lab 12.8 MB | C1..Cn (102.4 MB each)
//   primary needs C1..C6 -> 681 MB; fallback needs C1..C4 -> 476.2 MB
//   (round-0 session proved >= 501.76 MB available, so fallback always fits)
// ---------------------------------------------------------------------------
constexpr size_t B_RIGHT = 2560000;      // WP ends at 2,555,904
constexpr size_t B_LAB   = 53760000;
constexpr size_t B_B1    = 66560000;
constexpr size_t B_B2    = 168960000;
constexpr size_t B_B3    = 271360000;
constexpr size_t B_B4    = 373760000;
constexpr size_t B_B5    = 476160000;
constexpr size_t B_B6    = 578560000;
constexpr size_t WS_PRIMARY  = 680960000;
constexpr size_t WS_FALLBACK = 476160000;

extern "C" void kernel_launch(void* const* d_in, const int* in_sizes, int n_in,
                              void* d_out, int out_size, void* d_ws, size_t ws_size,
                              hipStream_t stream) {
  const float* features  = (const float*)d_in[0];
  const float* label_emb = (const float*)d_in[1];
  const float* wa     = (const float*)d_in[2];
  const float* ba     = (const float*)d_in[3];
  const float* w0     = (const float*)d_in[4];
  const float* b0     = (const float*)d_in[5];
  const float* wg1    = (const float*)d_in[6];
  const float* wg2    = (const float*)d_in[7];
  const float* w_last = (const float*)d_in[8];
  const float* b_last = (const float*)d_in[9];
  const float* a_out  = (const float*)d_in[10];
  const float* wl0    = (const float*)d_in[11];
  const float* bl0    = (const float*)d_in[12];
  const float* wl1    = (const float*)d_in[13];
  const float* bl1    = (const float*)d_in[14];
  const float* wl2    = (const float*)d_in[15];
  const float* bl2    = (const float*)d_in[16];
  const float* wl3    = (const float*)d_in[17];
  const float* bl3    = (const float*)d_in[18];
  const float* a_lab  = (const float*)d_in[19];

  if (ws_size < WS_FALLBACK) return;  // fail loudly (absmax) rather than corrupt

  char*  ws    = (char*)d_ws;
  short* WP    = (short*)ws;
  short* right = (short*)(ws + B_RIGHT);
  short* lab   = (short*)(ws + B_LAB);
  short* C1    = (short*)(ws + B_B1);
  short* C2    = (short*)(ws + B_B2);
  short* C3    = (short*)(ws + B_B3);
  short* C4    = (short*)(ws + B_B4);

  // 1. all packing in one launch: (W_END + N*64)/256 = 29992 blocks exactly
  uber_pack<<<dim3(29992), dim3(256), 0, stream>>>(
      w0, wg1, wg2, wl0, wl1, wl2, w_last, wl3, label_emb, WP, lab);

  // 2. attention
  attn_kernel<<<dim3(25000), dim3(256), 0, stream>>>(features, wa, ba, right);

  const dim3 blk(256);
  const dim3 gDual(782, 8), gSingle(782, 4), gFin(782, 1);

  if (ws_size >= WS_PRIMARY) {
    // ---------------- primary: 6-launch dual schedule ----------------
    short* C5 = (short*)(ws + B_B5);
    short* C6 = (short*)(ws + B_B6);
    // 3. layer0 (main) || layer0 (label)
    GArgs a0{right, WP + W_W0,  256, b0,  nullptr, C1, C2,      a_out};  // x0,sup1
    GArgs l0{lab,   WP + W_WL0,  64, bl0, nullptr, C5, nullptr, a_lab};  // y0
    gemm_dual<0, 4><<<gDual, blk, 0, stream>>>(a0, l0);
    // 4. layer1 (main) || layer1 (label)
    GArgs a1{C2, WP + W_WG1, 512, nullptr, C1, C3, C4,      a_out};      // x1,sup2
    GArgs l1{C5, WP + W_WL1, 512, bl1,    nullptr, C6, nullptr, a_lab};  // y1
    gemm_dual<1, 4><<<gDual, blk, 0, stream>>>(a1, l1);
    // 5. layer2 (main) || layer2 (label)
    GArgs a2{C4, WP + W_WG2, 512, nullptr, C3, C1, nullptr, a_out};      // p2
    GArgs l2{C6, WP + W_WL2, 512, bl2,    nullptr, C2, nullptr, a_lab};  // y2
    gemm_dual<2, 4><<<gDual, blk, 0, stream>>>(a2, l2);
    // 6. fused final: [p2|y2] @ [w_last;wl3] + b_last + bl3 -> d_out
    gemm_final<<<gFin, blk, 0, stream>>>(C1, C2, WP + W_FIN, b_last, bl3,
                                         (float*)d_out);
  } else {
    // ------------- fallback: 9-launch sequential, 4 buffers -------------
    // main chain: x0:C1, sup1:C2 -> x1:C3, sup2:C4 -> p2:C2 (sup1 dead)
    GArgs a0{right, WP + W_W0,  256, b0,      nullptr, C1, C2,      a_out};
    gemm_dual<0, 0><<<gSingle, blk, 0, stream>>>(a0, a0);
    GArgs a1{C2,    WP + W_WG1, 512, nullptr, C1,      C3, C4,      a_out};
    gemm_dual<1, 1><<<gSingle, blk, 0, stream>>>(a1, a1);
    GArgs a2{C4,    WP + W_WG2, 512, nullptr, C3,      C2, nullptr, a_out};
    gemm_dual<2, 2><<<gSingle, blk, 0, stream>>>(a2, a2);
    // label chain (reuses freed slots): y0:C1 (x0 dead) -> y1:C3 (x1 dead) -> y2:C1
    GArgs l0{lab, WP + W_WL0,  64, bl0, nullptr, C1, nullptr, a_lab};
    gemm_dual<4, 4><<<gSingle, blk, 0, stream>>>(l0, l0);
    GArgs l1{C1,  WP + W_WL1, 512, bl1, nullptr, C3, nullptr, a_lab};
    gemm_dual<4, 4><<<gSingle, blk, 0, stream>>>(l1, l1);
    GArgs l2{C3,  WP + W_WL2, 512, bl2, nullptr, C1, nullptr, a_lab};
    gemm_dual<4, 4><<<gSingle, blk, 0, stream>>>(l2, l2);
    // fused final: [p2|y2] -> d_out
    gemm_final<<<gFin, blk, 0, stream>>>(C2, C1, WP + W_FIN, b_last, bl3,
                                         (float*)d_out);
  }
}